// Round 4
// baseline (5074.943 us; speedup 1.0000x reference)
//
#include <hip/hip_runtime.h>
#include <hip/hip_bf16.h>
#include <float.h>

// Problem constants
#define Bn   16
#define Nn   32768
#define Cn   64
#define Sn   1024
#define Kn   32
#define Mn   48              // fp32 candidate count for fp64 rerank
#define On   1024
#define KCn  2048            // K*C
#define FEATS_ELEMS (Bn*On*Cn)          // 1,048,576
#define SAMP_ELEMS  (Bn*Sn*Cn)          // 1,048,576

// ws layout (bytes)
#define D2_OFF   0ull                               // 1024*32768*4 = 134,217,728  (reused as H)
#define H_OFF    0ull                               // 16*1024*2048*4 = same region
#define P2_OFF   134217728ull                       // 32768*4
#define NBR_OFF  (P2_OFF + 131072ull)               // 1024*32*4 = 131,072
#define CAND_OFF (NBR_OFF + 131072ull)              // 1024*48*4 = 196,608
#define PART_OFF (CAND_OFF + 196608ull)             // 4*16*1024*64*4 = 16,777,216
// total ws requirement: ~151.5 MB (prev run's 151.3 MB fit)

// ---------------------------------------------------------------- p2 = |x0_n|^2
__global__ __launch_bounds__(256) void p2_kernel(const float* __restrict__ x,
                                                 float* __restrict__ p2) {
  int n = blockIdx.x * 256 + threadIdx.x;
  const float* r = x + (size_t)n * Cn;
  float s = 0.f;
  #pragma unroll
  for (int c = 0; c < Cn; ++c) s += r[c] * r[c];
  p2[n] = s;
}

// ------------------------------------------------- d2[s][n] = q2 + p2 - 2*dot
__global__ __launch_bounds__(256) void dist_kernel(const float* __restrict__ x,
                                                   const int* __restrict__ sidx,
                                                   const float* __restrict__ p2,
                                                   float* __restrict__ d2) {
  const int n0 = blockIdx.x * 128;
  const int s0 = blockIdx.y * 128;
  __shared__ float Qs[64][129];   // [c][s_local]
  __shared__ float Ps[64][129];   // [c][n_local]
  __shared__ float sq2[128], sp2[128];
  __shared__ int   sIdx[128];
  const int t = threadIdx.x;
  const int tx = t & 15, ty = t >> 4;

  if (t < 128) { int ss = sidx[s0 + t]; sIdx[t] = ss; sq2[t] = p2[ss]; }
  else         { sp2[t - 128] = p2[n0 + t - 128]; }
  __syncthreads();

  #pragma unroll
  for (int r = 0; r < 32; ++r) {            // 8192 elements each for Q and P
    int id = r * 256 + t;
    int c_l = id & 63, r_l = id >> 6;
    Qs[c_l][r_l] = x[(size_t)sIdx[r_l] * Cn + c_l];
    Ps[c_l][r_l] = x[(size_t)(n0 + r_l) * Cn + c_l];
  }
  __syncthreads();

  float acc[8][8];
  #pragma unroll
  for (int i = 0; i < 8; ++i)
    #pragma unroll
    for (int j = 0; j < 8; ++j) acc[i][j] = 0.f;

  #pragma unroll 4
  for (int c = 0; c < 64; ++c) {
    float a[8], b[8];
    #pragma unroll
    for (int i = 0; i < 8; ++i) a[i] = Qs[c][ty * 8 + i];
    #pragma unroll
    for (int j = 0; j < 8; ++j) b[j] = Ps[c][tx * 8 + j];
    #pragma unroll
    for (int i = 0; i < 8; ++i)
      #pragma unroll
      for (int j = 0; j < 8; ++j) acc[i][j] += a[i] * b[j];
  }

  #pragma unroll
  for (int i = 0; i < 8; ++i) {
    int srow = s0 + ty * 8 + i;
    float q2v = sq2[ty * 8 + i];
    float out[8];
    #pragma unroll
    for (int j = 0; j < 8; ++j) out[j] = q2v + sp2[tx * 8 + j] - 2.f * acc[i][j];
    float4* dst = (float4*)&d2[(size_t)srow * Nn + n0 + tx * 8];
    dst[0] = make_float4(out[0], out[1], out[2], out[3]);
    dst[1] = make_float4(out[4], out[5], out[6], out[7]);
  }
}

// -------------------------------------- top-48 fp32 candidates per d2 row
// Candidate prefilter only: the exact top-32 (fp64) is a subset of the fp32
// top-48 with certainty (gap(32->48) ~0.2-3 vs fp32 noise ~1e-4).
__device__ __forceinline__ unsigned int f2key(float d) {
  unsigned int b = __float_as_uint(d);
  return (b & 0x80000000u) ? ~b : (b | 0x80000000u);
}

__global__ __launch_bounds__(256) void topk_kernel(const float* __restrict__ d2,
                                                   int* __restrict__ cand) {
  const int s = blockIdx.x;
  const float* row = d2 + (size_t)s * Nn;
  const int t = threadIdx.x;

  unsigned long long best[32];
  #pragma unroll
  for (int j = 0; j < 32; ++j) best[j] = ~0ull;
  unsigned long long worst = ~0ull;

  for (int i = t; i < Nn; i += 256) {
    float d = row[i];
    unsigned long long key = ((unsigned long long)f2key(d) << 32) | (unsigned)i;
    if (key < worst) {
      bool done = false;
      #pragma unroll
      for (int j = 0; j < 32; ++j)
        if (!done && best[j] == worst) { best[j] = key; done = true; }
      worst = 0ull;
      #pragma unroll
      for (int j = 0; j < 32; ++j) worst = best[j] > worst ? best[j] : worst;
    }
  }

  __shared__ unsigned long long wm[4];
  for (int r = 0; r < Mn; ++r) {
    unsigned long long lmin = best[0];
    #pragma unroll
    for (int j = 1; j < 32; ++j) lmin = best[j] < lmin ? best[j] : lmin;
    #pragma unroll
    for (int m = 32; m > 0; m >>= 1) {
      unsigned long long o = __shfl_xor(lmin, m, 64);
      lmin = o < lmin ? o : lmin;
    }
    if ((t & 63) == 0) wm[t >> 6] = lmin;
    __syncthreads();
    unsigned long long g = wm[0];
    #pragma unroll
    for (int w = 1; w < 4; ++w) g = wm[w] < g ? wm[w] : g;
    #pragma unroll
    for (int j = 0; j < 32; ++j) if (best[j] == g) best[j] = ~0ull;
    if (t == 0) cand[s * Mn + r] = (int)(g & 0xffffffffu);
    __syncthreads();
  }
}

// ---------------------- fp64 rerank: exact top-32 of the 48 fp32 candidates
// d2 = sum (q-p)^2 in fp64 (no cancellation; exact ranking to ~1e-13).
// Key = (d2_bits & ~0x7FFF) | idx : primary fp64 d2 (rel quantum 2^-37),
// ties -> lower index, matching jax.lax.top_k stability.
__global__ __launch_bounds__(64) void rerank_kernel(const float* __restrict__ x,
                                                    const int* __restrict__ sidx,
                                                    const int* __restrict__ cand,
                                                    int* __restrict__ nbr) {
  const int s = blockIdx.x;
  const int lane = threadIdx.x;          // 0..63 (one wave)
  __shared__ double q[64];
  q[lane] = (double)x[(size_t)sidx[s] * Cn + lane];
  __syncthreads();

  unsigned long long key = ~0ull;
  if (lane < Mn) {
    int ci = cand[s * Mn + lane];
    const float* p = x + (size_t)ci * Cn;
    double acc = 0.0;
    #pragma unroll
    for (int c = 0; c < 64; ++c) {
      double d = q[c] - (double)p[c];
      acc = fma(d, d, acc);
    }
    unsigned long long bits = __double_as_longlong(acc);   // acc >= 0
    key = (bits & ~0x7FFFull) | (unsigned long long)(unsigned)ci;
  }

  for (int r = 0; r < Kn; ++r) {
    unsigned long long m = key;
    #pragma unroll
    for (int w = 32; w > 0; w >>= 1) {
      unsigned long long o = __shfl_xor(m, w, 64);
      m = o < m ? o : m;
    }
    if (key == m) key = ~0ull;           // unique keys (distinct idx)
    if (lane == 0) nbr[s * Kn + r] = (int)(m & 0x7FFFull);
  }
}

// --------------------------------------------------- sampled_x gather (output)
__global__ __launch_bounds__(256) void sample_kernel(const float* __restrict__ x,
                                                     const int* __restrict__ sidx,
                                                     float* __restrict__ out2) {
  int i = blockIdx.x * 256 + threadIdx.x;     // B*S*C
  int c = i & 63;
  int s = (i >> 6) & (Sn - 1);
  int b = i >> 16;                            // S*C = 65536
  out2[i] = x[(size_t)b * Nn * Cn + (size_t)sidx[s] * Cn + c];
}

// ------------------- GEMM1: H[b][o][kc] = relu(b1[o] + sum_s W1[o,s]*G[s,kc])
// G[s,kc] = x[b, nbr[s, kc>>6], kc&63]   (gather fused into B-operand load)
__global__ __launch_bounds__(256) void gemm1_kernel(const float* __restrict__ x,
                                                    const float* __restrict__ W1,
                                                    const float* __restrict__ b1,
                                                    const int* __restrict__ nbr,
                                                    float* __restrict__ H) {
  const int b   = blockIdx.z;
  const int o0  = blockIdx.y * 128;
  const int kc0 = blockIdx.x * 128;
  __shared__ float As[32][129];   // [s_local][o_local]
  __shared__ float Bs[32][129];   // [s_local][kc_local]
  const int t = threadIdx.x;
  const int tx = t & 15, ty = t >> 4;
  const float* xb = x + (size_t)b * Nn * Cn;
  float* Hb = H + (size_t)b * On * KCn;

  float acc[8][8];
  #pragma unroll
  for (int i = 0; i < 8; ++i)
    #pragma unroll
    for (int j = 0; j < 8; ++j) acc[i][j] = 0.f;

  for (int s0 = 0; s0 < Sn; s0 += 32) {
    #pragma unroll
    for (int r = 0; r < 16; ++r) {            // A: W1 tile 128o x 32s -> As[s][o]
      int id = r * 256 + t;
      int s_l = id & 31, o_l = id >> 5;
      As[s_l][o_l] = W1[(size_t)(o0 + o_l) * Sn + s0 + s_l];
    }
    #pragma unroll
    for (int r = 0; r < 16; ++r) {            // B: gathered tile 32s x 128kc
      int id = r * 256 + t;
      int kc_l = id & 127, s_l = id >> 7;
      int kc = kc0 + kc_l;
      int nidx = nbr[(s0 + s_l) * Kn + (kc >> 6)];   // wave-uniform -> broadcast
      Bs[s_l][kc_l] = xb[(size_t)nidx * Cn + (kc & 63)];
    }
    __syncthreads();
    #pragma unroll 4
    for (int kk = 0; kk < 32; ++kk) {
      float a[8], bb[8];
      #pragma unroll
      for (int i = 0; i < 8; ++i) a[i] = As[kk][ty * 8 + i];
      #pragma unroll
      for (int j = 0; j < 8; ++j) bb[j] = Bs[kk][tx * 8 + j];
      #pragma unroll
      for (int i = 0; i < 8; ++i)
        #pragma unroll
        for (int j = 0; j < 8; ++j) acc[i][j] += a[i] * bb[j];
    }
    __syncthreads();
  }

  #pragma unroll
  for (int i = 0; i < 8; ++i) {
    int o = o0 + ty * 8 + i;
    float bias = b1[o];
    float out[8];
    #pragma unroll
    for (int j = 0; j < 8; ++j) {
      float v = acc[i][j] + bias;
      out[j] = v > 0.f ? v : 0.f;
    }
    float4* dst = (float4*)&Hb[(size_t)o * KCn + kc0 + tx * 8];
    dst[0] = make_float4(out[0], out[1], out[2], out[3]);
    dst[1] = make_float4(out[4], out[5], out[6], out[7]);
  }
}

// ---- GEMM2 + fused max over k (k-split=4):
// part[ks][b][p][c] = max_{k in ks*8..ks*8+8} sum_o W2[p,o]*H[b,o,k*64+c]
__global__ __launch_bounds__(256) void gemm2_kernel(const float* __restrict__ W2,
                                                    const float* __restrict__ H,
                                                    float* __restrict__ part) {
  const int b  = blockIdx.z;
  const int p0 = blockIdx.y * 128;
  const int ks = blockIdx.x;                 // 0..3
  __shared__ float Ws[32][129];   // [o_local][p_local]
  __shared__ float Hs[32][64];    // [o_local][c]
  const int t = threadIdx.x;
  const int tx = t & 15, ty = t >> 4;
  const float* Hb = H + (size_t)b * On * KCn;

  float km[8][4];
  #pragma unroll
  for (int i = 0; i < 8; ++i)
    #pragma unroll
    for (int j = 0; j < 4; ++j) km[i][j] = -FLT_MAX;

  for (int k = ks * 8; k < ks * 8 + 8; ++k) {
    float acc[8][4];
    #pragma unroll
    for (int i = 0; i < 8; ++i)
      #pragma unroll
      for (int j = 0; j < 4; ++j) acc[i][j] = 0.f;

    for (int o0 = 0; o0 < On; o0 += 32) {
      #pragma unroll
      for (int r = 0; r < 16; ++r) {          // W2 tile 128p x 32o -> Ws[o][p]
        int id = r * 256 + t;
        int o_l = id & 31, p_l = id >> 5;
        Ws[o_l][p_l] = W2[(size_t)(p0 + p_l) * On + o0 + o_l];
      }
      #pragma unroll
      for (int r = 0; r < 8; ++r) {           // H tile 32o x 64c
        int id = r * 256 + t;
        int c_l = id & 63, o_l = id >> 6;
        Hs[o_l][c_l] = Hb[(size_t)(o0 + o_l) * KCn + k * 64 + c_l];
      }
      __syncthreads();
      #pragma unroll 4
      for (int oo = 0; oo < 32; ++oo) {
        float a[8], bb[4];
        #pragma unroll
        for (int i = 0; i < 8; ++i) a[i] = Ws[oo][ty * 8 + i];
        #pragma unroll
        for (int j = 0; j < 4; ++j) bb[j] = Hs[oo][tx * 4 + j];
        #pragma unroll
        for (int i = 0; i < 8; ++i)
          #pragma unroll
          for (int j = 0; j < 4; ++j) acc[i][j] += a[i] * bb[j];
      }
      __syncthreads();
    }
    #pragma unroll
    for (int i = 0; i < 8; ++i)
      #pragma unroll
      for (int j = 0; j < 4; ++j) km[i][j] = fmaxf(km[i][j], acc[i][j]);
  }

  float* pb = part + (size_t)ks * Bn * On * Cn + (size_t)b * On * Cn;
  #pragma unroll
  for (int i = 0; i < 8; ++i) {
    int p = p0 + ty * 8 + i;
    float4* dst = (float4*)&pb[(size_t)p * Cn + tx * 4];
    dst[0] = make_float4(km[i][0], km[i][1], km[i][2], km[i][3]);
  }
}

// ------------------------------------------- combine partial maxes + bias b2
__global__ __launch_bounds__(256) void combine_kernel(const float* __restrict__ part,
                                                      const float* __restrict__ b2,
                                                      float* __restrict__ feats) {
  int i = blockIdx.x * 256 + threadIdx.x;     // B*OUT*C
  int p = (i >> 6) & (On - 1);
  float m = part[i];
  #pragma unroll
  for (int ks = 1; ks < 4; ++ks) m = fmaxf(m, part[(size_t)ks * FEATS_ELEMS + i]);
  feats[i] = m + b2[p];
}

extern "C" void kernel_launch(void* const* d_in, const int* in_sizes, int n_in,
                              void* d_out, int out_size, void* d_ws, size_t ws_size,
                              hipStream_t stream) {
  const float* x    = (const float*)d_in[0];
  const int*   sidx = (const int*)d_in[1];
  const float* W1   = (const float*)d_in[2];
  const float* b1   = (const float*)d_in[3];
  const float* W2   = (const float*)d_in[4];
  const float* b2   = (const float*)d_in[5];
  float* feats = (float*)d_out;                       // [B][OUT][C]
  float* out2  = (float*)d_out + FEATS_ELEMS;         // [B][S][C]

  char* ws = (char*)d_ws;
  float* d2   = (float*)(ws + D2_OFF);
  float* p2   = (float*)(ws + P2_OFF);
  int*   nbr  = (int*)  (ws + NBR_OFF);
  int*   cand = (int*)  (ws + CAND_OFF);
  float* part = (float*)(ws + PART_OFF);
  float* H    = (float*)(ws + H_OFF);                 // reuses d2 region

  // 1. p2
  p2_kernel<<<dim3(Nn / 256), dim3(256), 0, stream>>>(x, p2);
  // 2. d2 matrix (batch 0, fp32 prefilter)
  dist_kernel<<<dim3(Nn / 128, Sn / 128), dim3(256), 0, stream>>>(x, sidx, p2, d2);
  // 3. top-48 fp32 candidates per row
  topk_kernel<<<dim3(Sn), dim3(256), 0, stream>>>(d2, cand);
  // 4. exact fp64 rerank -> top-32 neighbor set
  rerank_kernel<<<dim3(Sn), dim3(64), 0, stream>>>(x, sidx, cand, nbr);
  // 5. sampled_x output
  sample_kernel<<<dim3(SAMP_ELEMS / 256), dim3(256), 0, stream>>>(x, sidx, out2);
  // 6. GEMM1 + bias + relu (gather fused), overwrites d2 region with H
  gemm1_kernel<<<dim3(KCn / 128, On / 128, Bn), dim3(256), 0, stream>>>(x, W1, b1, nbr, H);
  // 7. GEMM2 + fused max-over-k (k-split 4)
  gemm2_kernel<<<dim3(4, On / 128, Bn), dim3(256), 0, stream>>>(W2, H, part);
  // 8. combine + bias b2
  combine_kernel<<<dim3(FEATS_ELEMS / 256), dim3(256), 0, stream>>>(part, b2, feats);
}

// Round 5
// 1030.864 us; speedup vs baseline: 4.9230x; 4.9230x over previous
//
#include <hip/hip_runtime.h>
#include <hip/hip_bf16.h>
#include <float.h>

// Problem constants
#define Bn   16
#define Nn   32768
#define Cn   64
#define Sn   1024
#define Kn   32
#define Mn   48              // fp32 candidate count for fp64 rerank
#define On   1024
#define KCn  2048            // K*C
#define FEATS_ELEMS (Bn*On*Cn)          // 1,048,576
#define SAMP_ELEMS  (Bn*Sn*Cn)          // 1,048,576

typedef unsigned short u16;
typedef unsigned int   u32;
typedef short v8s __attribute__((ext_vector_type(8)));
typedef float v4f __attribute__((ext_vector_type(4)));

// ws layout (bytes).  d2 (KNN, 134.2MB @0) is temporally disjoint from
// HT+xb which reuse the same region after topk consumes d2.
#define HT_OFF   0ull                    // bf16 [16][2048][1024] = 67,108,864
#define XB_OFF   67108864ull             // bf16 [16][32768][64]  = 67,108,864
#define D2_OFF   0ull                    // fp32 [1024][32768]    = 134,217,728 (KNN phase only)
#define P2_OFF   134217728ull            // 131,072
#define NBR_OFF  134348800ull            // 131,072
#define CAND_OFF 134479872ull            // 196,608
#define W1H_OFF  134676480ull            // 2,097,152 each
#define W1L_OFF  136773632ull
#define W2H_OFF  138870784ull
#define W2L_OFF  140967936ull
// total ws requirement: ~143.1 MB (prev verified run used 151.5 MB)

__device__ __forceinline__ u16 rne16(float f) {       // fp32 -> bf16 RNE
  u32 u = __float_as_uint(f);
  return (u16)((u + 0x7FFFu + ((u >> 16) & 1u)) >> 16);
}
__device__ __forceinline__ v4f vmax4(v4f a, v4f b) {
  v4f r; r[0]=fmaxf(a[0],b[0]); r[1]=fmaxf(a[1],b[1]);
  r[2]=fmaxf(a[2],b[2]); r[3]=fmaxf(a[3],b[3]); return r;
}
union V16 { uint4 v; u32 u[4]; u16 s[8]; };
union V8  { uint2 v; u16 s[4]; };
union US4 { ushort4 v; u16 s[4]; };

// ---------------------------------------------------------------- p2 = |x0_n|^2
__global__ __launch_bounds__(256) void p2_kernel(const float* __restrict__ x,
                                                 float* __restrict__ p2) {
  int n = blockIdx.x * 256 + threadIdx.x;
  const float* r = x + (size_t)n * Cn;
  float s = 0.f;
  #pragma unroll
  for (int c = 0; c < Cn; ++c) s += r[c] * r[c];
  p2[n] = s;
}

// ------------------------------------------------- d2[s][n] = q2 + p2 - 2*dot
__global__ __launch_bounds__(256) void dist_kernel(const float* __restrict__ x,
                                                   const int* __restrict__ sidx,
                                                   const float* __restrict__ p2,
                                                   float* __restrict__ d2) {
  const int n0 = blockIdx.x * 128;
  const int s0 = blockIdx.y * 128;
  __shared__ float Qs[64][129];
  __shared__ float Ps[64][129];
  __shared__ float sq2[128], sp2[128];
  __shared__ int   sIdx[128];
  const int t = threadIdx.x;
  const int tx = t & 15, ty = t >> 4;

  if (t < 128) { int ss = sidx[s0 + t]; sIdx[t] = ss; sq2[t] = p2[ss]; }
  else         { sp2[t - 128] = p2[n0 + t - 128]; }
  __syncthreads();

  #pragma unroll
  for (int r = 0; r < 32; ++r) {
    int id = r * 256 + t;
    int c_l = id & 63, r_l = id >> 6;
    Qs[c_l][r_l] = x[(size_t)sIdx[r_l] * Cn + c_l];
    Ps[c_l][r_l] = x[(size_t)(n0 + r_l) * Cn + c_l];
  }
  __syncthreads();

  float acc[8][8];
  #pragma unroll
  for (int i = 0; i < 8; ++i)
    #pragma unroll
    for (int j = 0; j < 8; ++j) acc[i][j] = 0.f;

  #pragma unroll 4
  for (int c = 0; c < 64; ++c) {
    float a[8], b[8];
    #pragma unroll
    for (int i = 0; i < 8; ++i) a[i] = Qs[c][ty * 8 + i];
    #pragma unroll
    for (int j = 0; j < 8; ++j) b[j] = Ps[c][tx * 8 + j];
    #pragma unroll
    for (int i = 0; i < 8; ++i)
      #pragma unroll
      for (int j = 0; j < 8; ++j) acc[i][j] += a[i] * b[j];
  }

  #pragma unroll
  for (int i = 0; i < 8; ++i) {
    int srow = s0 + ty * 8 + i;
    float q2v = sq2[ty * 8 + i];
    float out[8];
    #pragma unroll
    for (int j = 0; j < 8; ++j) out[j] = q2v + sp2[tx * 8 + j] - 2.f * acc[i][j];
    float4* dst = (float4*)&d2[(size_t)srow * Nn + n0 + tx * 8];
    dst[0] = make_float4(out[0], out[1], out[2], out[3]);
    dst[1] = make_float4(out[4], out[5], out[6], out[7]);
  }
}

// -------------------------------------- top-48 fp32 candidates per d2 row
__device__ __forceinline__ u32 f2key(float d) {
  u32 b = __float_as_uint(d);
  return (b & 0x80000000u) ? ~b : (b | 0x80000000u);
}

__global__ __launch_bounds__(256) void topk_kernel(const float* __restrict__ d2,
                                                   int* __restrict__ cand) {
  const int s = blockIdx.x;
  const float* row = d2 + (size_t)s * Nn;
  const int t = threadIdx.x;

  unsigned long long best[32];
  #pragma unroll
  for (int j = 0; j < 32; ++j) best[j] = ~0ull;
  unsigned long long worst = ~0ull;

  for (int i = t; i < Nn; i += 256) {
    float d = row[i];
    unsigned long long key = ((unsigned long long)f2key(d) << 32) | (u32)i;
    if (key < worst) {
      bool done = false;
      #pragma unroll
      for (int j = 0; j < 32; ++j)
        if (!done && best[j] == worst) { best[j] = key; done = true; }
      worst = 0ull;
      #pragma unroll
      for (int j = 0; j < 32; ++j) worst = best[j] > worst ? best[j] : worst;
    }
  }

  __shared__ unsigned long long wm[4];
  for (int r = 0; r < Mn; ++r) {
    unsigned long long lmin = best[0];
    #pragma unroll
    for (int j = 1; j < 32; ++j) lmin = best[j] < lmin ? best[j] : lmin;
    #pragma unroll
    for (int m = 32; m > 0; m >>= 1) {
      unsigned long long o = __shfl_xor(lmin, m, 64);
      lmin = o < lmin ? o : lmin;
    }
    if ((t & 63) == 0) wm[t >> 6] = lmin;
    __syncthreads();
    unsigned long long g = wm[0];
    #pragma unroll
    for (int w = 1; w < 4; ++w) g = wm[w] < g ? wm[w] : g;
    #pragma unroll
    for (int j = 0; j < 32; ++j) if (best[j] == g) best[j] = ~0ull;
    if (t == 0) cand[s * Mn + r] = (int)(g & 0xffffffffu);
    __syncthreads();
  }
}

// ---------------------- fp64 rerank: exact top-32 of the 48 fp32 candidates
__global__ __launch_bounds__(64) void rerank_kernel(const float* __restrict__ x,
                                                    const int* __restrict__ sidx,
                                                    const int* __restrict__ cand,
                                                    int* __restrict__ nbr) {
  const int s = blockIdx.x;
  const int lane = threadIdx.x;
  __shared__ double q[64];
  q[lane] = (double)x[(size_t)sidx[s] * Cn + lane];
  __syncthreads();

  unsigned long long key = ~0ull;
  if (lane < Mn) {
    int ci = cand[s * Mn + lane];
    const float* p = x + (size_t)ci * Cn;
    double acc = 0.0;
    #pragma unroll
    for (int c = 0; c < 64; ++c) {
      double d = q[c] - (double)p[c];
      acc = fma(d, d, acc);
    }
    unsigned long long bits = __double_as_longlong(acc);
    key = (bits & ~0x7FFFull) | (unsigned long long)(u32)ci;
  }

  for (int r = 0; r < Kn; ++r) {
    unsigned long long m = key;
    #pragma unroll
    for (int w = 32; w > 0; w >>= 1) {
      unsigned long long o = __shfl_xor(m, w, 64);
      m = o < m ? o : m;
    }
    if (key == m) key = ~0ull;
    if (lane == 0) nbr[s * Kn + r] = (int)(m & 0x7FFFull);
  }
}

// --------------------------------------------------- sampled_x gather (output)
__global__ __launch_bounds__(256) void sample_kernel(const float* __restrict__ x,
                                                     const int* __restrict__ sidx,
                                                     float* __restrict__ out2) {
  int i = blockIdx.x * 256 + threadIdx.x;
  int c = i & 63;
  int s = (i >> 6) & (Sn - 1);
  int b = i >> 16;
  out2[i] = x[(size_t)b * Nn * Cn + (size_t)sidx[s] * Cn + c];
}

// ------------------------------------------------ x fp32 -> bf16 (RNE), 8/thread
__global__ __launch_bounds__(256) void cvt_x_kernel(const float* __restrict__ x,
                                                    u16* __restrict__ xb) {
  size_t i = ((size_t)blockIdx.x * 256 + threadIdx.x) * 8;
  float4 f0 = *(const float4*)(x + i);
  float4 f1 = *(const float4*)(x + i + 4);
  uint4 o;
  o.x = (u32)rne16(f0.x) | ((u32)rne16(f0.y) << 16);
  o.y = (u32)rne16(f0.z) | ((u32)rne16(f0.w) << 16);
  o.z = (u32)rne16(f1.x) | ((u32)rne16(f1.y) << 16);
  o.w = (u32)rne16(f1.z) | ((u32)rne16(f1.w) << 16);
  *(uint4*)(xb + i) = o;
}

// --------------------------- W fp32 -> bf16 hi + bf16 lo (split), 4/thread
__global__ __launch_bounds__(256) void cvt_split_kernel(const float* __restrict__ src,
                                                        u16* __restrict__ dh,
                                                        u16* __restrict__ dl) {
  size_t i = ((size_t)blockIdx.x * 256 + threadIdx.x) * 4;
  float4 f = *(const float4*)(src + i);
  float fv[4] = {f.x, f.y, f.z, f.w};
  V8 oh, ol;
  #pragma unroll
  for (int j = 0; j < 4; ++j) {
    u16 h = rne16(fv[j]);
    float hf = __uint_as_float((u32)h << 16);
    oh.s[j] = h;
    ol.s[j] = rne16(fv[j] - hf);
  }
  *(uint2*)(dh + i) = oh.v;
  *(uint2*)(dl + i) = ol.v;
}

// ---------------- GEMM1 (MFMA): HT[b][kc][o] = relu(b1[o] + sum_s W1[o,s]*G[s,kc])
// A = W1 (hi+lo split), B = gathered x (bf16). 128x128 tile, BK=32,
// 4 waves (2x2), 4x4 16x16x32 fragments per wave, 2 MFMA combos (Ah*B, Al*B).
__global__ __launch_bounds__(256) void gemm1_mfma(const u16* __restrict__ xb,
                                                  const u16* __restrict__ W1h,
                                                  const u16* __restrict__ W1l,
                                                  const float* __restrict__ b1,
                                                  const int* __restrict__ nbr,
                                                  u16* __restrict__ HT) {
  const int b = blockIdx.z, o0 = blockIdx.y * 128, kc0 = blockIdx.x * 128;
  __shared__ u16 Ah[128 * 32];      // [m][k] row-major, k contiguous
  __shared__ u16 Al[128 * 32];
  __shared__ u16 Bs[128 * 32];      // [n][k] (transposed during staging)
  __shared__ float b1s[128];
  const int t = threadIdx.x, lane = t & 63, w = t >> 6;
  const int wr = w >> 1, wc = w & 1;
  if (t < 128) b1s[t] = b1[o0 + t];

  v4f acc[4][4];
  #pragma unroll
  for (int i = 0; i < 4; ++i)
    #pragma unroll
    for (int j = 0; j < 4; ++j) { v4f z = {0.f,0.f,0.f,0.f}; acc[i][j] = z; }

  // A staging: thread covers row t>>1, k-chunk (t&1)*16 (16 elems = 2 uint4)
  const u16* aSrcH = W1h + (size_t)(o0 + (t >> 1)) * Sn + (t & 1) * 16;
  const u16* aSrcL = W1l + (size_t)(o0 + (t >> 1)) * Sn + (t & 1) * 16;
  // B staging: j=t&15 -> s2 = 2j (even s), nchunk = t>>4 -> n0 = nchunk*8
  const int bj = t & 15, nchunk = t >> 4;
  const int s2 = bj * 2;
  const int n0 = nchunk * 8;
  const int kknn = (kc0 + n0) >> 6;          // knn index (same for 8 n's)
  const int cc = (kc0 + n0) & 63;            // c offset, multiple of 8
  const u16* xbb = xb + (size_t)b * Nn * Cn;

  for (int s0 = 0; s0 < Sn; s0 += 32) {
    // issue global loads for this K-step (before barrier: overlaps prior compute drain)
    int r0 = nbr[(s0 + s2) * Kn + kknn];
    int r1 = nbr[(s0 + s2 + 1) * Kn + kknn];
    V16 bv0, bv1, av0, av1;
    bv0.v = *(const uint4*)(xbb + (size_t)r0 * Cn + cc);
    bv1.v = *(const uint4*)(xbb + (size_t)r1 * Cn + cc);
    av0.v = *(const uint4*)(aSrcH + s0);
    av1.v = *(const uint4*)(aSrcL + s0);
    uint4 av0b = *(const uint4*)(aSrcH + s0 + 8);
    uint4 av1b = *(const uint4*)(aSrcL + s0 + 8);
    __syncthreads();                          // prior iteration's frag reads done
    *(uint4*)&Ah[t * 16] = av0.v; *(uint4*)&Ah[t * 16 + 8] = av0b;
    *(uint4*)&Al[t * 16] = av1.v; *(uint4*)&Al[t * 16 + 8] = av1b;
    #pragma unroll
    for (int i = 0; i < 8; ++i) {             // Bs[n0+i][s2], k-pair packed u32
      *(u32*)&Bs[(n0 + i) * 32 + s2] = (u32)bv0.s[i] | ((u32)bv1.s[i] << 16);
    }
    __syncthreads();

    v8s afh[4], afl[4], bf[4];
    const int lm = lane & 15, ko = (lane >> 4) * 8;
    #pragma unroll
    for (int i = 0; i < 4; ++i) {
      afh[i] = *(v8s*)&Ah[(wr * 64 + i * 16 + lm) * 32 + ko];
      afl[i] = *(v8s*)&Al[(wr * 64 + i * 16 + lm) * 32 + ko];
      bf[i]  = *(v8s*)&Bs[(wc * 64 + i * 16 + lm) * 32 + ko];
    }
    #pragma unroll
    for (int mi = 0; mi < 4; ++mi)
      #pragma unroll
      for (int nj = 0; nj < 4; ++nj) {
        acc[mi][nj] = __builtin_amdgcn_mfma_f32_16x16x32_bf16(afh[mi], bf[nj], acc[mi][nj], 0, 0, 0);
        acc[mi][nj] = __builtin_amdgcn_mfma_f32_16x16x32_bf16(afl[mi], bf[nj], acc[mi][nj], 0, 0, 0);
      }
  }

  // epilogue: relu(acc + b1) -> bf16, write HT[kc][o] (4 consecutive o per lane)
  const size_t HTb = (size_t)b * KCn * On;
  const int lm = lane & 15;
  const int orow = wr * 64 + (lane >> 4) * 4;
  #pragma unroll
  for (int mi = 0; mi < 4; ++mi) {
    #pragma unroll
    for (int nj = 0; nj < 4; ++nj) {
      int kc = kc0 + wc * 64 + nj * 16 + lm;
      int om = orow + mi * 16;
      US4 outp;
      #pragma unroll
      for (int r = 0; r < 4; ++r) {
        float v = acc[mi][nj][r] + b1s[om + r];
        v = v > 0.f ? v : 0.f;
        outp.s[r] = rne16(v);
      }
      *(ushort4*)&HT[HTb + (size_t)kc * On + o0 + om] = outp.v;
    }
  }
}

// ------- GEMM2 (MFMA) + in-register max over k, writes feats directly.
// feats[b][p][c] = b2[p] + max_k sum_o W2[p,o]*H[b,o,k*64+c]
// B-tile columns n: k = n&31, cq = n>>5  (4 c per block), B rows from HT.
__global__ __launch_bounds__(256) void gemm2_mfma(const u16* __restrict__ HT,
                                                  const u16* __restrict__ W2h,
                                                  const u16* __restrict__ W2l,
                                                  const float* __restrict__ b2,
                                                  float* __restrict__ feats) {
  const int b = blockIdx.z, p0 = blockIdx.y * 128, c0 = blockIdx.x * 4;
  __shared__ u16 Ah[128 * 32];
  __shared__ u16 Al[128 * 32];
  __shared__ u16 Bs[128 * 32];      // [n][k(o)] rows contiguous in o
  __shared__ float b2s[128];
  const int t = threadIdx.x, lane = t & 63, w = t >> 6;
  const int wr = w >> 1, wc = w & 1;
  if (t < 128) b2s[t] = b2[p0 + t];

  v4f acc[4][4];
  #pragma unroll
  for (int i = 0; i < 4; ++i)
    #pragma unroll
    for (int j = 0; j < 4; ++j) { v4f z = {0.f,0.f,0.f,0.f}; acc[i][j] = z; }

  const u16* aSrcH = W2h + (size_t)(p0 + (t >> 1)) * On + (t & 1) * 16;
  const u16* aSrcL = W2l + (size_t)(p0 + (t >> 1)) * On + (t & 1) * 16;
  const int nrow = t >> 1;                    // B row 0..127
  const int kcn = (nrow & 31) * 64 + c0 + (nrow >> 5);
  const u16* bSrc = HT + (size_t)b * KCn * On + (size_t)kcn * On + (t & 1) * 16;

  for (int o0k = 0; o0k < On; o0k += 32) {
    V16 a0, a1, b0;
    a0.v = *(const uint4*)(aSrcH + o0k);
    a1.v = *(const uint4*)(aSrcL + o0k);
    b0.v = *(const uint4*)(bSrc + o0k);
    uint4 a0b = *(const uint4*)(aSrcH + o0k + 8);
    uint4 a1b = *(const uint4*)(aSrcL + o0k + 8);
    uint4 b0b = *(const uint4*)(bSrc + o0k + 8);
    __syncthreads();
    *(uint4*)&Ah[t * 16] = a0.v; *(uint4*)&Ah[t * 16 + 8] = a0b;
    *(uint4*)&Al[t * 16] = a1.v; *(uint4*)&Al[t * 16 + 8] = a1b;
    *(uint4*)&Bs[t * 16] = b0.v; *(uint4*)&Bs[t * 16 + 8] = b0b;
    __syncthreads();

    v8s afh[4], afl[4], bf[4];
    const int lm = lane & 15, ko = (lane >> 4) * 8;
    #pragma unroll
    for (int i = 0; i < 4; ++i) {
      afh[i] = *(v8s*)&Ah[(wr * 64 + i * 16 + lm) * 32 + ko];
      afl[i] = *(v8s*)&Al[(wr * 64 + i * 16 + lm) * 32 + ko];
      bf[i]  = *(v8s*)&Bs[(wc * 64 + i * 16 + lm) * 32 + ko];
    }
    #pragma unroll
    for (int mi = 0; mi < 4; ++mi)
      #pragma unroll
      for (int nj = 0; nj < 4; ++nj) {
        acc[mi][nj] = __builtin_amdgcn_mfma_f32_16x16x32_bf16(afh[mi], bf[nj], acc[mi][nj], 0, 0, 0);
        acc[mi][nj] = __builtin_amdgcn_mfma_f32_16x16x32_bf16(afl[mi], bf[nj], acc[mi][nj], 0, 0, 0);
      }
  }

  // epilogue: max over k (32 values) fully in-register, + b2, direct feats write.
  // frag nj cols: k = (nj&1)*16 + (lane&15), cq = wc*2 + (nj>>1)
  const int lm = lane & 15;
  const int prow = wr * 64 + (lane >> 4) * 4;
  #pragma unroll
  for (int mi = 0; mi < 4; ++mi) {
    v4f m0 = vmax4(acc[mi][0], acc[mi][1]);   // cq = wc*2     : k = {lm, 16+lm}
    v4f m1 = vmax4(acc[mi][2], acc[mi][3]);   // cq = wc*2 + 1
    float v0[4], v1[4];
    #pragma unroll
    for (int r = 0; r < 4; ++r) {
      float a0 = m0[r], a1 = m1[r];
      #pragma unroll
      for (int msk = 1; msk < 16; msk <<= 1) {
        a0 = fmaxf(a0, __shfl_xor(a0, msk, 64));
        a1 = fmaxf(a1, __shfl_xor(a1, msk, 64));
      }
      v0[r] = a0; v1[r] = a1;
    }
    if (lm == 0) {
      #pragma unroll
      for (int r = 0; r < 4; ++r) {
        int p = prow + mi * 16 + r;
        float bias = b2s[p];
        size_t base = ((size_t)b * On + p0 + p) * Cn + c0 + wc * 2;
        feats[base]     = v0[r] + bias;
        feats[base + 1] = v1[r] + bias;
      }
    }
  }
}

extern "C" void kernel_launch(void* const* d_in, const int* in_sizes, int n_in,
                              void* d_out, int out_size, void* d_ws, size_t ws_size,
                              hipStream_t stream) {
  const float* x    = (const float*)d_in[0];
  const int*   sidx = (const int*)d_in[1];
  const float* W1   = (const float*)d_in[2];
  const float* b1   = (const float*)d_in[3];
  const float* W2   = (const float*)d_in[4];
  const float* b2   = (const float*)d_in[5];
  float* feats = (float*)d_out;                       // [B][OUT][C]
  float* out2  = (float*)d_out + FEATS_ELEMS;         // [B][S][C]

  char* ws = (char*)d_ws;
  float* d2  = (float*)(ws + D2_OFF);
  float* p2  = (float*)(ws + P2_OFF);
  int*   nbr = (int*)  (ws + NBR_OFF);
  int*   cand= (int*)  (ws + CAND_OFF);
  u16*   HT  = (u16*)  (ws + HT_OFF);
  u16*   xb  = (u16*)  (ws + XB_OFF);
  u16*   W1h = (u16*)  (ws + W1H_OFF);
  u16*   W1l = (u16*)  (ws + W1L_OFF);
  u16*   W2h = (u16*)  (ws + W2H_OFF);
  u16*   W2l = (u16*)  (ws + W2L_OFF);

  // KNN phase (identical to verified round-4 kernel)
  p2_kernel<<<dim3(Nn / 256), dim3(256), 0, stream>>>(x, p2);
  dist_kernel<<<dim3(Nn / 128, Sn / 128), dim3(256), 0, stream>>>(x, sidx, p2, d2);
  topk_kernel<<<dim3(Sn), dim3(256), 0, stream>>>(d2, cand);
  rerank_kernel<<<dim3(Sn), dim3(64), 0, stream>>>(x, sidx, cand, nbr);
  // conversions (xb overwrites upper half of dead d2 region)
  cvt_x_kernel<<<dim3((Bn * Nn * Cn) / (256 * 8)), dim3(256), 0, stream>>>(x, xb);
  cvt_split_kernel<<<dim3((On * Sn) / (256 * 4)), dim3(256), 0, stream>>>(W1, W1h, W1l);
  cvt_split_kernel<<<dim3((On * On) / (256 * 4)), dim3(256), 0, stream>>>(W2, W2h, W2l);
  sample_kernel<<<dim3(SAMP_ELEMS / 256), dim3(256), 0, stream>>>(x, sidx, out2);
  // MFMA GEMMs (HT overwrites lower half of dead d2 region)
  gemm1_mfma<<<dim3(KCn / 128, On / 128, Bn), dim3(256), 0, stream>>>(xb, W1h, W1l, b1, nbr, HT);
  gemm2_mfma<<<dim3(Cn / 4, On / 128, Bn), dim3(256), 0, stream>>>(HT, W2h, W2l, b2, feats);
}

// Round 6
// 839.731 us; speedup vs baseline: 6.0435x; 1.2276x over previous
//
#include <hip/hip_runtime.h>
#include <hip/hip_bf16.h>
#include <float.h>

// Problem constants
#define Bn   16
#define Nn   32768
#define Cn   64
#define Sn   1024
#define Kn   32
#define On   1024
#define KCn  2048            // K*C
#define TGT  48              // candidate rank target for fp64 rerank
#define MAXC 384             // candidate list capacity per row
#define FEATS_ELEMS (Bn*On*Cn)          // 1,048,576
#define SAMP_ELEMS  (Bn*Sn*Cn)          // 1,048,576

typedef unsigned short u16;
typedef unsigned int   u32;
typedef short v8s __attribute__((ext_vector_type(8)));
typedef float v4f __attribute__((ext_vector_type(4)));

// ws layout (bytes).  d2 (KNN, 134.2MB @0) is temporally disjoint from
// HT+xb which reuse the same region after select consumes d2.
#define HT_OFF   0ull                    // bf16 [16][2048][1024] = 67,108,864
#define XB_OFF   67108864ull             // bf16 [16][32768][64]  = 67,108,864
#define D2_OFF   0ull                    // fp32 [1024][32768]    = 134,217,728 (KNN phase only)
#define P2_OFF   134217728ull            // 131,072
#define NBR_OFF  134348800ull            // 131,072
#define W1H_OFF  134676480ull            // 2,097,152 each
#define W1L_OFF  136773632ull
#define W2H_OFF  138870784ull
#define W2L_OFF  140967936ull
#define CAND_OFF 143065088ull            // 1024*384*4 = 1,572,864
#define CNT_OFF  144637952ull            // 1024*4
// total ws requirement: ~144.7 MB (prev verified runs used up to 151.5 MB)

__device__ __forceinline__ u16 rne16(float f) {       // fp32 -> bf16 RNE
  u32 u = __float_as_uint(f);
  return (u16)((u + 0x7FFFu + ((u >> 16) & 1u)) >> 16);
}
__device__ __forceinline__ v4f vmax4(v4f a, v4f b) {
  v4f r; r[0]=fmaxf(a[0],b[0]); r[1]=fmaxf(a[1],b[1]);
  r[2]=fmaxf(a[2],b[2]); r[3]=fmaxf(a[3],b[3]); return r;
}
union V16 { uint4 v; u32 u[4]; u16 s[8]; };
union V8  { uint2 v; u16 s[4]; };
union US4 { ushort4 v; u16 s[4]; };

// ---------------------------------------------------------------- p2 = |x0_n|^2
__global__ __launch_bounds__(256) void p2_kernel(const float* __restrict__ x,
                                                 float* __restrict__ p2) {
  int n = blockIdx.x * 256 + threadIdx.x;
  const float* r = x + (size_t)n * Cn;
  float s = 0.f;
  #pragma unroll
  for (int c = 0; c < Cn; ++c) s += r[c] * r[c];
  p2[n] = s;
}

// ------------------------------------------------- d2[s][n] = q2 + p2 - 2*dot
__global__ __launch_bounds__(256) void dist_kernel(const float* __restrict__ x,
                                                   const int* __restrict__ sidx,
                                                   const float* __restrict__ p2,
                                                   float* __restrict__ d2) {
  const int n0 = blockIdx.x * 128;
  const int s0 = blockIdx.y * 128;
  __shared__ float Qs[64][129];
  __shared__ float Ps[64][129];
  __shared__ float sq2[128], sp2[128];
  __shared__ int   sIdx[128];
  const int t = threadIdx.x;
  const int tx = t & 15, ty = t >> 4;

  if (t < 128) { int ss = sidx[s0 + t]; sIdx[t] = ss; sq2[t] = p2[ss]; }
  else         { sp2[t - 128] = p2[n0 + t - 128]; }
  __syncthreads();

  #pragma unroll
  for (int r = 0; r < 32; ++r) {
    int id = r * 256 + t;
    int c_l = id & 63, r_l = id >> 6;
    Qs[c_l][r_l] = x[(size_t)sIdx[r_l] * Cn + c_l];
    Ps[c_l][r_l] = x[(size_t)(n0 + r_l) * Cn + c_l];
  }
  __syncthreads();

  float acc[8][8];
  #pragma unroll
  for (int i = 0; i < 8; ++i)
    #pragma unroll
    for (int j = 0; j < 8; ++j) acc[i][j] = 0.f;

  #pragma unroll 4
  for (int c = 0; c < 64; ++c) {
    float a[8], b[8];
    #pragma unroll
    for (int i = 0; i < 8; ++i) a[i] = Qs[c][ty * 8 + i];
    #pragma unroll
    for (int j = 0; j < 8; ++j) b[j] = Ps[c][tx * 8 + j];
    #pragma unroll
    for (int i = 0; i < 8; ++i)
      #pragma unroll
      for (int j = 0; j < 8; ++j) acc[i][j] += a[i] * b[j];
  }

  #pragma unroll
  for (int i = 0; i < 8; ++i) {
    int srow = s0 + ty * 8 + i;
    float q2v = sq2[ty * 8 + i];
    float out[8];
    #pragma unroll
    for (int j = 0; j < 8; ++j) out[j] = q2v + sp2[tx * 8 + j] - 2.f * acc[i][j];
    float4* dst = (float4*)&d2[(size_t)srow * Nn + n0 + tx * 8];
    dst[0] = make_float4(out[0], out[1], out[2], out[3]);
    dst[1] = make_float4(out[4], out[5], out[6], out[7]);
  }
}

// ---------------- candidate select: two-level histogram radix-select.
// Finds a 22-bit key-prefix threshold whose cumulative count >= TGT and
// compacts every index at-or-below it (unordered). The fp64 rerank then
// extracts the exact top-32, so candidate ORDER is irrelevant; only
// set-inclusion of the true top-32 matters (margin: >= 16 ranks >> fp32 noise).
__device__ __forceinline__ u32 f2key(float d) {
  u32 b = __float_as_uint(d);
  return (b & 0x80000000u) ? ~b : (b | 0x80000000u);
}

__global__ __launch_bounds__(256) void select_kernel(const float* __restrict__ d2,
                                                     int* __restrict__ cand,
                                                     int* __restrict__ candcnt) {
  const int s = blockIdx.x;
  const float* row = d2 + (size_t)s * Nn;
  const int t = threadIdx.x;
  __shared__ u32 hist[2048];
  __shared__ u32 partial[256];
  __shared__ u32 bc[4];           // [0]=b1, [1]=cum-before-b1, [2]=thr22, [3]=count

  // ---- pass A: level-1 histogram (key bits [31:21])
  #pragma unroll
  for (int i = 0; i < 8; ++i) hist[t * 8 + i] = 0;
  __syncthreads();
  for (int i = t; i < Nn; i += 256)
    atomicAdd(&hist[f2key(row[i]) >> 21], 1u);
  __syncthreads();

  u32 lsum = 0;
  #pragma unroll
  for (int i = 0; i < 8; ++i) lsum += hist[t * 8 + i];
  partial[t] = lsum;
  __syncthreads();
  for (int off = 1; off < 256; off <<= 1) {
    u32 add = (t >= off) ? partial[t - off] : 0;
    __syncthreads();
    partial[t] += add;
    __syncthreads();
  }
  {
    u32 c = (t == 0) ? 0 : partial[t - 1];
    #pragma unroll
    for (int i = 0; i < 8; ++i) {
      u32 h = hist[t * 8 + i];
      if (c < TGT && c + h >= TGT) { bc[0] = t * 8 + i; bc[1] = c; }
      c += h;
    }
  }
  __syncthreads();
  const u32 b1 = bc[0], cumb = bc[1];
  const u32 rem = TGT - cumb;                 // in [1, TGT]

  // ---- pass B: level-2 histogram within bin b1 (key bits [20:10])
  __syncthreads();
  #pragma unroll
  for (int i = 0; i < 8; ++i) hist[t * 8 + i] = 0;
  __syncthreads();
  for (int i = t; i < Nn; i += 256) {
    u32 key = f2key(row[i]);
    if ((key >> 21) == b1) atomicAdd(&hist[(key >> 10) & 0x7FFu], 1u);
  }
  __syncthreads();

  lsum = 0;
  #pragma unroll
  for (int i = 0; i < 8; ++i) lsum += hist[t * 8 + i];
  partial[t] = lsum;
  __syncthreads();
  for (int off = 1; off < 256; off <<= 1) {
    u32 add = (t >= off) ? partial[t - off] : 0;
    __syncthreads();
    partial[t] += add;
    __syncthreads();
  }
  {
    u32 c = (t == 0) ? 0 : partial[t - 1];
    #pragma unroll
    for (int i = 0; i < 8; ++i) {
      u32 h = hist[t * 8 + i];
      if (c < rem && c + h >= rem) bc[2] = (b1 << 11) | (t * 8 + i);
      c += h;
    }
  }
  if (t == 0) bc[3] = 0;
  __syncthreads();
  const u32 thr22 = bc[2];

  // ---- pass C: compact candidates (22-bit prefix <= thr22)
  for (int i = t; i < Nn; i += 256) {
    u32 key = f2key(row[i]);
    if ((key >> 10) <= thr22) {
      u32 pos = atomicAdd(&bc[3], 1u);
      if (pos < MAXC) cand[s * MAXC + pos] = i;
    }
  }
  __syncthreads();
  if (t == 0) candcnt[s] = (int)(bc[3] < MAXC ? bc[3] : MAXC);
}

// ---------------------- fp64 rerank: exact top-32 of the candidate list.
// d2 = sum (q-p)^2 in fp64 (no cancellation; exact to ~1e-13 relative).
// Key = (d2_bits & ~0x7FFF) | idx : ties -> lower index (top_k stability).
__global__ __launch_bounds__(64) void rerank_kernel(const float* __restrict__ x,
                                                    const int* __restrict__ sidx,
                                                    const int* __restrict__ cand,
                                                    const int* __restrict__ candcnt,
                                                    int* __restrict__ nbr) {
  const int s = blockIdx.x;
  const int lane = threadIdx.x;
  __shared__ double q[64];
  q[lane] = (double)x[(size_t)sidx[s] * Cn + lane];
  __syncthreads();

  const int cnt = candcnt[s];
  const int niter = (cnt + 63) >> 6;          // <= 6
  unsigned long long keys[MAXC / 64];
  #pragma unroll
  for (int it = 0; it < MAXC / 64; ++it) keys[it] = ~0ull;

  for (int it = 0; it < niter; ++it) {
    int idx = it * 64 + lane;
    if (idx < cnt) {
      int ci = cand[s * MAXC + idx];
      const float* p = x + (size_t)ci * Cn;
      double acc = 0.0;
      #pragma unroll
      for (int c = 0; c < 64; ++c) {
        double d = q[c] - (double)p[c];
        acc = fma(d, d, acc);
      }
      unsigned long long bits = __double_as_longlong(acc);
      keys[it] = (bits & ~0x7FFFull) | (unsigned long long)(u32)ci;
    }
  }

  for (int r = 0; r < Kn; ++r) {
    unsigned long long m = keys[0];
    #pragma unroll
    for (int it = 1; it < MAXC / 64; ++it) m = keys[it] < m ? keys[it] : m;
    #pragma unroll
    for (int w = 32; w > 0; w >>= 1) {
      unsigned long long o = __shfl_xor(m, w, 64);
      m = o < m ? o : m;
    }
    #pragma unroll
    for (int it = 0; it < MAXC / 64; ++it)
      if (keys[it] == m) keys[it] = ~0ull;    // keys unique (distinct idx)
    if (lane == 0) nbr[s * Kn + r] = (int)(m & 0x7FFFull);
  }
}

// --------------------------------------------------- sampled_x gather (output)
__global__ __launch_bounds__(256) void sample_kernel(const float* __restrict__ x,
                                                     const int* __restrict__ sidx,
                                                     float* __restrict__ out2) {
  int i = blockIdx.x * 256 + threadIdx.x;
  int c = i & 63;
  int s = (i >> 6) & (Sn - 1);
  int b = i >> 16;
  out2[i] = x[(size_t)b * Nn * Cn + (size_t)sidx[s] * Cn + c];
}

// ------------------------------------------------ x fp32 -> bf16 (RNE), 8/thread
__global__ __launch_bounds__(256) void cvt_x_kernel(const float* __restrict__ x,
                                                    u16* __restrict__ xb) {
  size_t i = ((size_t)blockIdx.x * 256 + threadIdx.x) * 8;
  float4 f0 = *(const float4*)(x + i);
  float4 f1 = *(const float4*)(x + i + 4);
  uint4 o;
  o.x = (u32)rne16(f0.x) | ((u32)rne16(f0.y) << 16);
  o.y = (u32)rne16(f0.z) | ((u32)rne16(f0.w) << 16);
  o.z = (u32)rne16(f1.x) | ((u32)rne16(f1.y) << 16);
  o.w = (u32)rne16(f1.z) | ((u32)rne16(f1.w) << 16);
  *(uint4*)(xb + i) = o;
}

// --------------------------- W fp32 -> bf16 hi + bf16 lo (split), 4/thread
__global__ __launch_bounds__(256) void cvt_split_kernel(const float* __restrict__ src,
                                                        u16* __restrict__ dh,
                                                        u16* __restrict__ dl) {
  size_t i = ((size_t)blockIdx.x * 256 + threadIdx.x) * 4;
  float4 f = *(const float4*)(src + i);
  float fv[4] = {f.x, f.y, f.z, f.w};
  V8 oh, ol;
  #pragma unroll
  for (int j = 0; j < 4; ++j) {
    u16 h = rne16(fv[j]);
    float hf = __uint_as_float((u32)h << 16);
    oh.s[j] = h;
    ol.s[j] = rne16(fv[j] - hf);
  }
  *(uint2*)(dh + i) = oh.v;
  *(uint2*)(dl + i) = ol.v;
}

// ---------------- GEMM1 (MFMA): HT[b][kc][o] = relu(b1[o] + sum_s W1[o,s]*G[s,kc])
// A = W1 (hi+lo split), B = gathered x (bf16). 128x128 tile, BK=32,
// 4 waves (2x2), 4x4 16x16x32 fragments per wave, 2 MFMA combos (Ah*B, Al*B).
__global__ __launch_bounds__(256) void gemm1_mfma(const u16* __restrict__ xb,
                                                  const u16* __restrict__ W1h,
                                                  const u16* __restrict__ W1l,
                                                  const float* __restrict__ b1,
                                                  const int* __restrict__ nbr,
                                                  u16* __restrict__ HT) {
  const int b = blockIdx.z, o0 = blockIdx.y * 128, kc0 = blockIdx.x * 128;
  __shared__ u16 Ah[128 * 32];      // [m][k] row-major, k contiguous
  __shared__ u16 Al[128 * 32];
  __shared__ u16 Bs[128 * 32];      // [n][k] (transposed during staging)
  __shared__ float b1s[128];
  const int t = threadIdx.x, lane = t & 63, w = t >> 6;
  const int wr = w >> 1, wc = w & 1;
  if (t < 128) b1s[t] = b1[o0 + t];

  v4f acc[4][4];
  #pragma unroll
  for (int i = 0; i < 4; ++i)
    #pragma unroll
    for (int j = 0; j < 4; ++j) { v4f z = {0.f,0.f,0.f,0.f}; acc[i][j] = z; }

  const u16* aSrcH = W1h + (size_t)(o0 + (t >> 1)) * Sn + (t & 1) * 16;
  const u16* aSrcL = W1l + (size_t)(o0 + (t >> 1)) * Sn + (t & 1) * 16;
  const int bj = t & 15, nchunk = t >> 4;
  const int s2 = bj * 2;
  const int n0 = nchunk * 8;
  const int kknn = (kc0 + n0) >> 6;
  const int cc = (kc0 + n0) & 63;
  const u16* xbb = xb + (size_t)b * Nn * Cn;

  for (int s0 = 0; s0 < Sn; s0 += 32) {
    int r0 = nbr[(s0 + s2) * Kn + kknn];
    int r1 = nbr[(s0 + s2 + 1) * Kn + kknn];
    V16 bv0, bv1, av0, av1;
    bv0.v = *(const uint4*)(xbb + (size_t)r0 * Cn + cc);
    bv1.v = *(const uint4*)(xbb + (size_t)r1 * Cn + cc);
    av0.v = *(const uint4*)(aSrcH + s0);
    av1.v = *(const uint4*)(aSrcL + s0);
    uint4 av0b = *(const uint4*)(aSrcH + s0 + 8);
    uint4 av1b = *(const uint4*)(aSrcL + s0 + 8);
    __syncthreads();
    *(uint4*)&Ah[t * 16] = av0.v; *(uint4*)&Ah[t * 16 + 8] = av0b;
    *(uint4*)&Al[t * 16] = av1.v; *(uint4*)&Al[t * 16 + 8] = av1b;
    #pragma unroll
    for (int i = 0; i < 8; ++i) {
      *(u32*)&Bs[(n0 + i) * 32 + s2] = (u32)bv0.s[i] | ((u32)bv1.s[i] << 16);
    }
    __syncthreads();

    v8s afh[4], afl[4], bf[4];
    const int lm = lane & 15, ko = (lane >> 4) * 8;
    #pragma unroll
    for (int i = 0; i < 4; ++i) {
      afh[i] = *(v8s*)&Ah[(wr * 64 + i * 16 + lm) * 32 + ko];
      afl[i] = *(v8s*)&Al[(wr * 64 + i * 16 + lm) * 32 + ko];
      bf[i]  = *(v8s*)&Bs[(wc * 64 + i * 16 + lm) * 32 + ko];
    }
    #pragma unroll
    for (int mi = 0; mi < 4; ++mi)
      #pragma unroll
      for (int nj = 0; nj < 4; ++nj) {
        acc[mi][nj] = __builtin_amdgcn_mfma_f32_16x16x32_bf16(afh[mi], bf[nj], acc[mi][nj], 0, 0, 0);
        acc[mi][nj] = __builtin_amdgcn_mfma_f32_16x16x32_bf16(afl[mi], bf[nj], acc[mi][nj], 0, 0, 0);
      }
  }

  const size_t HTb = (size_t)b * KCn * On;
  const int lm = lane & 15;
  const int orow = wr * 64 + (lane >> 4) * 4;
  #pragma unroll
  for (int mi = 0; mi < 4; ++mi) {
    #pragma unroll
    for (int nj = 0; nj < 4; ++nj) {
      int kc = kc0 + wc * 64 + nj * 16 + lm;
      int om = orow + mi * 16;
      US4 outp;
      #pragma unroll
      for (int r = 0; r < 4; ++r) {
        float v = acc[mi][nj][r] + b1s[om + r];
        v = v > 0.f ? v : 0.f;
        outp.s[r] = rne16(v);
      }
      *(ushort4*)&HT[HTb + (size_t)kc * On + o0 + om] = outp.v;
    }
  }
}

// ------- GEMM2 (MFMA) + in-register max over k, writes feats directly.
// feats[b][p][c] = b2[p] + max_k sum_o W2[p,o]*H[b,o,k*64+c]
// B-tile columns n: k = n&31, cq = n>>5  (4 c per block), B rows from HT.
__global__ __launch_bounds__(256) void gemm2_mfma(const u16* __restrict__ HT,
                                                  const u16* __restrict__ W2h,
                                                  const u16* __restrict__ W2l,
                                                  const float* __restrict__ b2,
                                                  float* __restrict__ feats) {
  const int b = blockIdx.z, p0 = blockIdx.y * 128, c0 = blockIdx.x * 4;
  __shared__ u16 Ah[128 * 32];
  __shared__ u16 Al[128 * 32];
  __shared__ u16 Bs[128 * 32];
  __shared__ float b2s[128];
  const int t = threadIdx.x, lane = t & 63, w = t >> 6;
  const int wr = w >> 1, wc = w & 1;
  if (t < 128) b2s[t] = b2[p0 + t];

  v4f acc[4][4];
  #pragma unroll
  for (int i = 0; i < 4; ++i)
    #pragma unroll
    for (int j = 0; j < 4; ++j) { v4f z = {0.f,0.f,0.f,0.f}; acc[i][j] = z; }

  const u16* aSrcH = W2h + (size_t)(p0 + (t >> 1)) * On + (t & 1) * 16;
  const u16* aSrcL = W2l + (size_t)(p0 + (t >> 1)) * On + (t & 1) * 16;
  const int nrow = t >> 1;
  const int kcn = (nrow & 31) * 64 + c0 + (nrow >> 5);
  const u16* bSrc = HT + (size_t)b * KCn * On + (size_t)kcn * On + (t & 1) * 16;

  for (int o0k = 0; o0k < On; o0k += 32) {
    V16 a0, a1, b0;
    a0.v = *(const uint4*)(aSrcH + o0k);
    a1.v = *(const uint4*)(aSrcL + o0k);
    b0.v = *(const uint4*)(bSrc + o0k);
    uint4 a0b = *(const uint4*)(aSrcH + o0k + 8);
    uint4 a1b = *(const uint4*)(aSrcL + o0k + 8);
    uint4 b0b = *(const uint4*)(bSrc + o0k + 8);
    __syncthreads();
    *(uint4*)&Ah[t * 16] = a0.v; *(uint4*)&Ah[t * 16 + 8] = a0b;
    *(uint4*)&Al[t * 16] = a1.v; *(uint4*)&Al[t * 16 + 8] = a1b;
    *(uint4*)&Bs[t * 16] = b0.v; *(uint4*)&Bs[t * 16 + 8] = b0b;
    __syncthreads();

    v8s afh[4], afl[4], bf[4];
    const int lm = lane & 15, ko = (lane >> 4) * 8;
    #pragma unroll
    for (int i = 0; i < 4; ++i) {
      afh[i] = *(v8s*)&Ah[(wr * 64 + i * 16 + lm) * 32 + ko];
      afl[i] = *(v8s*)&Al[(wr * 64 + i * 16 + lm) * 32 + ko];
      bf[i]  = *(v8s*)&Bs[(wc * 64 + i * 16 + lm) * 32 + ko];
    }
    #pragma unroll
    for (int mi = 0; mi < 4; ++mi)
      #pragma unroll
      for (int nj = 0; nj < 4; ++nj) {
        acc[mi][nj] = __builtin_amdgcn_mfma_f32_16x16x32_bf16(afh[mi], bf[nj], acc[mi][nj], 0, 0, 0);
        acc[mi][nj] = __builtin_amdgcn_mfma_f32_16x16x32_bf16(afl[mi], bf[nj], acc[mi][nj], 0, 0, 0);
      }
  }

  const int lm = lane & 15;
  const int prow = wr * 64 + (lane >> 4) * 4;
  #pragma unroll
  for (int mi = 0; mi < 4; ++mi) {
    v4f m0 = vmax4(acc[mi][0], acc[mi][1]);
    v4f m1 = vmax4(acc[mi][2], acc[mi][3]);
    float v0[4], v1[4];
    #pragma unroll
    for (int r = 0; r < 4; ++r) {
      float a0 = m0[r], a1 = m1[r];
      #pragma unroll
      for (int msk = 1; msk < 16; msk <<= 1) {
        a0 = fmaxf(a0, __shfl_xor(a0, msk, 64));
        a1 = fmaxf(a1, __shfl_xor(a1, msk, 64));
      }
      v0[r] = a0; v1[r] = a1;
    }
    if (lm == 0) {
      #pragma unroll
      for (int r = 0; r < 4; ++r) {
        int p = prow + mi * 16 + r;
        float bias = b2s[p];
        size_t base = ((size_t)b * On + p0 + p) * Cn + c0 + wc * 2;
        feats[base]     = v0[r] + bias;
        feats[base + 1] = v1[r] + bias;
      }
    }
  }
}

extern "C" void kernel_launch(void* const* d_in, const int* in_sizes, int n_in,
                              void* d_out, int out_size, void* d_ws, size_t ws_size,
                              hipStream_t stream) {
  const float* x    = (const float*)d_in[0];
  const int*   sidx = (const int*)d_in[1];
  const float* W1   = (const float*)d_in[2];
  const float* b1   = (const float*)d_in[3];
  const float* W2   = (const float*)d_in[4];
  const float* b2   = (const float*)d_in[5];
  float* feats = (float*)d_out;                       // [B][OUT][C]
  float* out2  = (float*)d_out + FEATS_ELEMS;         // [B][S][C]

  char* ws = (char*)d_ws;
  float* d2   = (float*)(ws + D2_OFF);
  float* p2   = (float*)(ws + P2_OFF);
  int*   nbr  = (int*)  (ws + NBR_OFF);
  int*   cand = (int*)  (ws + CAND_OFF);
  int*   ccnt = (int*)  (ws + CNT_OFF);
  u16*   HT   = (u16*)  (ws + HT_OFF);
  u16*   xb   = (u16*)  (ws + XB_OFF);
  u16*   W1h  = (u16*)  (ws + W1H_OFF);
  u16*   W1l  = (u16*)  (ws + W1L_OFF);
  u16*   W2h  = (u16*)  (ws + W2H_OFF);
  u16*   W2l  = (u16*)  (ws + W2L_OFF);

  // KNN phase
  p2_kernel<<<dim3(Nn / 256), dim3(256), 0, stream>>>(x, p2);
  dist_kernel<<<dim3(Nn / 128, Sn / 128), dim3(256), 0, stream>>>(x, sidx, p2, d2);
  select_kernel<<<dim3(Sn), dim3(256), 0, stream>>>(d2, cand, ccnt);
  rerank_kernel<<<dim3(Sn), dim3(64), 0, stream>>>(x, sidx, cand, ccnt, nbr);
  // conversions (xb/HT overwrite the dead d2 region)
  cvt_x_kernel<<<dim3((Bn * Nn * Cn) / (256 * 8)), dim3(256), 0, stream>>>(x, xb);
  cvt_split_kernel<<<dim3((On * Sn) / (256 * 4)), dim3(256), 0, stream>>>(W1, W1h, W1l);
  cvt_split_kernel<<<dim3((On * On) / (256 * 4)), dim3(256), 0, stream>>>(W2, W2h, W2l);
  sample_kernel<<<dim3(SAMP_ELEMS / 256), dim3(256), 0, stream>>>(x, sidx, out2);
  // MFMA GEMMs
  gemm1_mfma<<<dim3(KCn / 128, On / 128, Bn), dim3(256), 0, stream>>>(xb, W1h, W1l, b1, nbr, HT);
  gemm2_mfma<<<dim3(Cn / 4, On / 128, Bn), dim3(256), 0, stream>>>(HT, W2h, W2l, b2, feats);
}

// Round 7
// 839.220 us; speedup vs baseline: 6.0472x; 1.0006x over previous
//
#include <hip/hip_runtime.h>
#include <hip/hip_bf16.h>
#include <float.h>

// Problem constants
#define Bn   16
#define Nn   32768
#define Cn   64
#define Sn   1024
#define Kn   32
#define On   1024
#define KCn  2048            // K*C
#define TGT  48              // candidate rank target for fp64 rerank
#define MAXC 384             // candidate list capacity per row
#define LDA  40              // padded LDS row stride (u16): 80B -> bank-conflict-free
#define FEATS_ELEMS (Bn*On*Cn)          // 1,048,576
#define SAMP_ELEMS  (Bn*Sn*Cn)          // 1,048,576

typedef unsigned short u16;
typedef unsigned int   u32;
typedef short v8s __attribute__((ext_vector_type(8)));
typedef float v4f __attribute__((ext_vector_type(4)));

// ws layout (bytes).  d2 (KNN, 134.2MB @0) is temporally disjoint from
// HT+xb which reuse the same region after select consumes d2.
#define HT_OFF   0ull                    // bf16 [16][2048][1024] = 67,108,864
#define XB_OFF   67108864ull             // bf16 [16][32768][64]  = 67,108,864
#define D2_OFF   0ull                    // fp32 [1024][32768]    = 134,217,728 (KNN phase only)
#define P2_OFF   134217728ull            // 131,072
#define NBR_OFF  134348800ull            // 131,072
#define W1H_OFF  134676480ull            // 2,097,152 each
#define W1L_OFF  136773632ull
#define W2H_OFF  138870784ull
#define W2L_OFF  140967936ull
#define CAND_OFF 143065088ull            // 1024*384*4 = 1,572,864
#define CNT_OFF  144637952ull            // 1024*4
// total ws requirement: ~144.7 MB (prev verified runs used up to 151.5 MB)

__device__ __forceinline__ u16 rne16(float f) {       // fp32 -> bf16 RNE
  u32 u = __float_as_uint(f);
  return (u16)((u + 0x7FFFu + ((u >> 16) & 1u)) >> 16);
}
__device__ __forceinline__ v4f vmax4(v4f a, v4f b) {
  v4f r; r[0]=fmaxf(a[0],b[0]); r[1]=fmaxf(a[1],b[1]);
  r[2]=fmaxf(a[2],b[2]); r[3]=fmaxf(a[3],b[3]); return r;
}
union V16 { uint4 v; u32 u[4]; u16 s[8]; };
union V8  { uint2 v; u16 s[4]; };
union US4 { ushort4 v; u16 s[4]; };

// ---------------------------------------------------------------- p2 = |x0_n|^2
__global__ __launch_bounds__(256) void p2_kernel(const float* __restrict__ x,
                                                 float* __restrict__ p2) {
  int n = blockIdx.x * 256 + threadIdx.x;
  const float* r = x + (size_t)n * Cn;
  float s = 0.f;
  #pragma unroll
  for (int c = 0; c < Cn; ++c) s += r[c] * r[c];
  p2[n] = s;
}

// ------------------------------------------------- d2[s][n] = q2 + p2 - 2*dot
__global__ __launch_bounds__(256) void dist_kernel(const float* __restrict__ x,
                                                   const int* __restrict__ sidx,
                                                   const float* __restrict__ p2,
                                                   float* __restrict__ d2) {
  const int n0 = blockIdx.x * 128;
  const int s0 = blockIdx.y * 128;
  __shared__ float Qs[64][129];
  __shared__ float Ps[64][129];
  __shared__ float sq2[128], sp2[128];
  __shared__ int   sIdx[128];
  const int t = threadIdx.x;
  const int tx = t & 15, ty = t >> 4;

  if (t < 128) { int ss = sidx[s0 + t]; sIdx[t] = ss; sq2[t] = p2[ss]; }
  else         { sp2[t - 128] = p2[n0 + t - 128]; }
  __syncthreads();

  #pragma unroll
  for (int r = 0; r < 32; ++r) {
    int id = r * 256 + t;
    int c_l = id & 63, r_l = id >> 6;
    Qs[c_l][r_l] = x[(size_t)sIdx[r_l] * Cn + c_l];
    Ps[c_l][r_l] = x[(size_t)(n0 + r_l) * Cn + c_l];
  }
  __syncthreads();

  float acc[8][8];
  #pragma unroll
  for (int i = 0; i < 8; ++i)
    #pragma unroll
    for (int j = 0; j < 8; ++j) acc[i][j] = 0.f;

  #pragma unroll 4
  for (int c = 0; c < 64; ++c) {
    float a[8], b[8];
    #pragma unroll
    for (int i = 0; i < 8; ++i) a[i] = Qs[c][ty * 8 + i];
    #pragma unroll
    for (int j = 0; j < 8; ++j) b[j] = Ps[c][tx * 8 + j];
    #pragma unroll
    for (int i = 0; i < 8; ++i)
      #pragma unroll
      for (int j = 0; j < 8; ++j) acc[i][j] += a[i] * b[j];
  }

  #pragma unroll
  for (int i = 0; i < 8; ++i) {
    int srow = s0 + ty * 8 + i;
    float q2v = sq2[ty * 8 + i];
    float out[8];
    #pragma unroll
    for (int j = 0; j < 8; ++j) out[j] = q2v + sp2[tx * 8 + j] - 2.f * acc[i][j];
    float4* dst = (float4*)&d2[(size_t)srow * Nn + n0 + tx * 8];
    dst[0] = make_float4(out[0], out[1], out[2], out[3]);
    dst[1] = make_float4(out[4], out[5], out[6], out[7]);
  }
}

// ---------------- candidate select: two-level histogram radix-select.
__device__ __forceinline__ u32 f2key(float d) {
  u32 b = __float_as_uint(d);
  return (b & 0x80000000u) ? ~b : (b | 0x80000000u);
}

__global__ __launch_bounds__(256) void select_kernel(const float* __restrict__ d2,
                                                     int* __restrict__ cand,
                                                     int* __restrict__ candcnt) {
  const int s = blockIdx.x;
  const float* row = d2 + (size_t)s * Nn;
  const int t = threadIdx.x;
  __shared__ u32 hist[2048];
  __shared__ u32 partial[256];
  __shared__ u32 bc[4];           // [0]=b1, [1]=cum-before-b1, [2]=thr22, [3]=count

  // ---- pass A: level-1 histogram (key bits [31:21])
  #pragma unroll
  for (int i = 0; i < 8; ++i) hist[t * 8 + i] = 0;
  __syncthreads();
  for (int i = t; i < Nn; i += 256)
    atomicAdd(&hist[f2key(row[i]) >> 21], 1u);
  __syncthreads();

  u32 lsum = 0;
  #pragma unroll
  for (int i = 0; i < 8; ++i) lsum += hist[t * 8 + i];
  partial[t] = lsum;
  __syncthreads();
  for (int off = 1; off < 256; off <<= 1) {
    u32 add = (t >= off) ? partial[t - off] : 0;
    __syncthreads();
    partial[t] += add;
    __syncthreads();
  }
  {
    u32 c = (t == 0) ? 0 : partial[t - 1];
    #pragma unroll
    for (int i = 0; i < 8; ++i) {
      u32 h = hist[t * 8 + i];
      if (c < TGT && c + h >= TGT) { bc[0] = t * 8 + i; bc[1] = c; }
      c += h;
    }
  }
  __syncthreads();
  const u32 b1 = bc[0], cumb = bc[1];
  const u32 rem = TGT - cumb;                 // in [1, TGT]

  // ---- pass B: level-2 histogram within bin b1 (key bits [20:10])
  __syncthreads();
  #pragma unroll
  for (int i = 0; i < 8; ++i) hist[t * 8 + i] = 0;
  __syncthreads();
  for (int i = t; i < Nn; i += 256) {
    u32 key = f2key(row[i]);
    if ((key >> 21) == b1) atomicAdd(&hist[(key >> 10) & 0x7FFu], 1u);
  }
  __syncthreads();

  lsum = 0;
  #pragma unroll
  for (int i = 0; i < 8; ++i) lsum += hist[t * 8 + i];
  partial[t] = lsum;
  __syncthreads();
  for (int off = 1; off < 256; off <<= 1) {
    u32 add = (t >= off) ? partial[t - off] : 0;
    __syncthreads();
    partial[t] += add;
    __syncthreads();
  }
  {
    u32 c = (t == 0) ? 0 : partial[t - 1];
    #pragma unroll
    for (int i = 0; i < 8; ++i) {
      u32 h = hist[t * 8 + i];
      if (c < rem && c + h >= rem) bc[2] = (b1 << 11) | (t * 8 + i);
      c += h;
    }
  }
  if (t == 0) bc[3] = 0;
  __syncthreads();
  const u32 thr22 = bc[2];

  // ---- pass C: compact candidates (22-bit prefix <= thr22)
  for (int i = t; i < Nn; i += 256) {
    u32 key = f2key(row[i]);
    if ((key >> 10) <= thr22) {
      u32 pos = atomicAdd(&bc[3], 1u);
      if (pos < MAXC) cand[s * MAXC + pos] = i;
    }
  }
  __syncthreads();
  if (t == 0) candcnt[s] = (int)(bc[3] < MAXC ? bc[3] : MAXC);
}

// ---------------------- fp64 rerank: exact top-32 of the candidate list.
__global__ __launch_bounds__(64) void rerank_kernel(const float* __restrict__ x,
                                                    const int* __restrict__ sidx,
                                                    const int* __restrict__ cand,
                                                    const int* __restrict__ candcnt,
                                                    int* __restrict__ nbr) {
  const int s = blockIdx.x;
  const int lane = threadIdx.x;
  __shared__ double q[64];
  q[lane] = (double)x[(size_t)sidx[s] * Cn + lane];
  __syncthreads();

  const int cnt = candcnt[s];
  const int niter = (cnt + 63) >> 6;          // <= 6
  unsigned long long keys[MAXC / 64];
  #pragma unroll
  for (int it = 0; it < MAXC / 64; ++it) keys[it] = ~0ull;

  for (int it = 0; it < niter; ++it) {
    int idx = it * 64 + lane;
    if (idx < cnt) {
      int ci = cand[s * MAXC + idx];
      const float* p = x + (size_t)ci * Cn;
      double acc = 0.0;
      #pragma unroll
      for (int c = 0; c < 64; ++c) {
        double d = q[c] - (double)p[c];
        acc = fma(d, d, acc);
      }
      unsigned long long bits = __double_as_longlong(acc);
      keys[it] = (bits & ~0x7FFFull) | (unsigned long long)(u32)ci;
    }
  }

  for (int r = 0; r < Kn; ++r) {
    unsigned long long m = keys[0];
    #pragma unroll
    for (int it = 1; it < MAXC / 64; ++it) m = keys[it] < m ? keys[it] : m;
    #pragma unroll
    for (int w = 32; w > 0; w >>= 1) {
      unsigned long long o = __shfl_xor(m, w, 64);
      m = o < m ? o : m;
    }
    #pragma unroll
    for (int it = 0; it < MAXC / 64; ++it)
      if (keys[it] == m) keys[it] = ~0ull;    // keys unique (distinct idx)
    if (lane == 0) nbr[s * Kn + r] = (int)(m & 0x7FFFull);
  }
}

// --------------------------------------------------- sampled_x gather (output)
__global__ __launch_bounds__(256) void sample_kernel(const float* __restrict__ x,
                                                     const int* __restrict__ sidx,
                                                     float* __restrict__ out2) {
  int i = blockIdx.x * 256 + threadIdx.x;
  int c = i & 63;
  int s = (i >> 6) & (Sn - 1);
  int b = i >> 16;
  out2[i] = x[(size_t)b * Nn * Cn + (size_t)sidx[s] * Cn + c];
}

// ------------------------------------------------ x fp32 -> bf16 (RNE), 8/thread
__global__ __launch_bounds__(256) void cvt_x_kernel(const float* __restrict__ x,
                                                    u16* __restrict__ xb) {
  size_t i = ((size_t)blockIdx.x * 256 + threadIdx.x) * 8;
  float4 f0 = *(const float4*)(x + i);
  float4 f1 = *(const float4*)(x + i + 4);
  uint4 o;
  o.x = (u32)rne16(f0.x) | ((u32)rne16(f0.y) << 16);
  o.y = (u32)rne16(f0.z) | ((u32)rne16(f0.w) << 16);
  o.z = (u32)rne16(f1.x) | ((u32)rne16(f1.y) << 16);
  o.w = (u32)rne16(f1.z) | ((u32)rne16(f1.w) << 16);
  *(uint4*)(xb + i) = o;
}

// --------------------------- W fp32 -> bf16 hi + bf16 lo (split), 4/thread
__global__ __launch_bounds__(256) void cvt_split_kernel(const float* __restrict__ src,
                                                        u16* __restrict__ dh,
                                                        u16* __restrict__ dl) {
  size_t i = ((size_t)blockIdx.x * 256 + threadIdx.x) * 4;
  float4 f = *(const float4*)(src + i);
  float fv[4] = {f.x, f.y, f.z, f.w};
  V8 oh, ol;
  #pragma unroll
  for (int j = 0; j < 4; ++j) {
    u16 h = rne16(fv[j]);
    float hf = __uint_as_float((u32)h << 16);
    oh.s[j] = h;
    ol.s[j] = rne16(fv[j] - hf);
  }
  *(uint2*)(dh + i) = oh.v;
  *(uint2*)(dl + i) = ol.v;
}

// ---------------- GEMM1 (MFMA): HT[b][kc][o] = relu(b1[o] + sum_s W1[o,s]*G[s,kc])
// A = W1 (hi+lo split), B = gathered x (bf16). 128x128 tile, BK=32,
// 4 waves (2x2), 4x4 16x16x32 fragments per wave, 2 MFMA combos (Ah*B, Al*B).
// LDS rows padded to LDA=40 u16 (80B): frag-read bank starts (20r+4g)%32
// tile all 32 banks (2-way max aliasing = free), vs 8-way at 64B stride.
__global__ __launch_bounds__(256) void gemm1_mfma(const u16* __restrict__ xb,
                                                  const u16* __restrict__ W1h,
                                                  const u16* __restrict__ W1l,
                                                  const float* __restrict__ b1,
                                                  const int* __restrict__ nbr,
                                                  u16* __restrict__ HT) {
  const int b = blockIdx.z, o0 = blockIdx.y * 128, kc0 = blockIdx.x * 128;
  __shared__ u16 Ah[128 * LDA];     // [m][k] row-major, k contiguous, padded
  __shared__ u16 Al[128 * LDA];
  __shared__ u16 Bs[128 * LDA];     // [n][k] (transposed during staging)
  __shared__ float b1s[128];
  const int t = threadIdx.x, lane = t & 63, w = t >> 6;
  const int wr = w >> 1, wc = w & 1;
  if (t < 128) b1s[t] = b1[o0 + t];

  v4f acc[4][4];
  #pragma unroll
  for (int i = 0; i < 4; ++i)
    #pragma unroll
    for (int j = 0; j < 4; ++j) { v4f z = {0.f,0.f,0.f,0.f}; acc[i][j] = z; }

  const u16* aSrcH = W1h + (size_t)(o0 + (t >> 1)) * Sn + (t & 1) * 16;
  const u16* aSrcL = W1l + (size_t)(o0 + (t >> 1)) * Sn + (t & 1) * 16;
  const int arow = (t >> 1) * LDA + (t & 1) * 16;     // LDS A/Al write base
  const int bj = t & 15, nchunk = t >> 4;
  const int s2 = bj * 2;
  const int n0 = nchunk * 8;
  const int kknn = (kc0 + n0) >> 6;
  const int cc = (kc0 + n0) & 63;
  const u16* xbb = xb + (size_t)b * Nn * Cn;

  for (int s0 = 0; s0 < Sn; s0 += 32) {
    int r0 = nbr[(s0 + s2) * Kn + kknn];
    int r1 = nbr[(s0 + s2 + 1) * Kn + kknn];
    V16 bv0, bv1, av0, av1;
    bv0.v = *(const uint4*)(xbb + (size_t)r0 * Cn + cc);
    bv1.v = *(const uint4*)(xbb + (size_t)r1 * Cn + cc);
    av0.v = *(const uint4*)(aSrcH + s0);
    av1.v = *(const uint4*)(aSrcL + s0);
    uint4 av0b = *(const uint4*)(aSrcH + s0 + 8);
    uint4 av1b = *(const uint4*)(aSrcL + s0 + 8);
    __syncthreads();
    *(uint4*)&Ah[arow] = av0.v; *(uint4*)&Ah[arow + 8] = av0b;
    *(uint4*)&Al[arow] = av1.v; *(uint4*)&Al[arow + 8] = av1b;
    #pragma unroll
    for (int i = 0; i < 8; ++i) {
      *(u32*)&Bs[(n0 + i) * LDA + s2] = (u32)bv0.s[i] | ((u32)bv1.s[i] << 16);
    }
    __syncthreads();

    v8s afh[4], afl[4], bf[4];
    const int lm = lane & 15, ko = (lane >> 4) * 8;
    #pragma unroll
    for (int i = 0; i < 4; ++i) {
      afh[i] = *(v8s*)&Ah[(wr * 64 + i * 16 + lm) * LDA + ko];
      afl[i] = *(v8s*)&Al[(wr * 64 + i * 16 + lm) * LDA + ko];
      bf[i]  = *(v8s*)&Bs[(wc * 64 + i * 16 + lm) * LDA + ko];
    }
    #pragma unroll
    for (int mi = 0; mi < 4; ++mi)
      #pragma unroll
      for (int nj = 0; nj < 4; ++nj) {
        acc[mi][nj] = __builtin_amdgcn_mfma_f32_16x16x32_bf16(afh[mi], bf[nj], acc[mi][nj], 0, 0, 0);
        acc[mi][nj] = __builtin_amdgcn_mfma_f32_16x16x32_bf16(afl[mi], bf[nj], acc[mi][nj], 0, 0, 0);
      }
  }

  const size_t HTb = (size_t)b * KCn * On;
  const int lm = lane & 15;
  const int orow = wr * 64 + (lane >> 4) * 4;
  #pragma unroll
  for (int mi = 0; mi < 4; ++mi) {
    #pragma unroll
    for (int nj = 0; nj < 4; ++nj) {
      int kc = kc0 + wc * 64 + nj * 16 + lm;
      int om = orow + mi * 16;
      US4 outp;
      #pragma unroll
      for (int r = 0; r < 4; ++r) {
        float v = acc[mi][nj][r] + b1s[om + r];
        v = v > 0.f ? v : 0.f;
        outp.s[r] = rne16(v);
      }
      *(ushort4*)&HT[HTb + (size_t)kc * On + o0 + om] = outp.v;
    }
  }
}

// ------- GEMM2 (MFMA) + in-register max over k, writes feats directly.
// feats[b][p][c] = b2[p] + max_k sum_o W2[p,o]*H[b,o,k*64+c]
// B-tile columns n: k = n&31, cq = n>>5  (4 c per block), B rows from HT.
__global__ __launch_bounds__(256) void gemm2_mfma(const u16* __restrict__ HT,
                                                  const u16* __restrict__ W2h,
                                                  const u16* __restrict__ W2l,
                                                  const float* __restrict__ b2,
                                                  float* __restrict__ feats) {
  const int b = blockIdx.z, p0 = blockIdx.y * 128, c0 = blockIdx.x * 4;
  __shared__ u16 Ah[128 * LDA];
  __shared__ u16 Al[128 * LDA];
  __shared__ u16 Bs[128 * LDA];
  __shared__ float b2s[128];
  const int t = threadIdx.x, lane = t & 63, w = t >> 6;
  const int wr = w >> 1, wc = w & 1;
  if (t < 128) b2s[t] = b2[p0 + t];

  v4f acc[4][4];
  #pragma unroll
  for (int i = 0; i < 4; ++i)
    #pragma unroll
    for (int j = 0; j < 4; ++j) { v4f z = {0.f,0.f,0.f,0.f}; acc[i][j] = z; }

  const u16* aSrcH = W2h + (size_t)(p0 + (t >> 1)) * On + (t & 1) * 16;
  const u16* aSrcL = W2l + (size_t)(p0 + (t >> 1)) * On + (t & 1) * 16;
  const int arow = (t >> 1) * LDA + (t & 1) * 16;
  const int nrow = t >> 1;
  const int kcn = (nrow & 31) * 64 + c0 + (nrow >> 5);
  const u16* bSrc = HT + (size_t)b * KCn * On + (size_t)kcn * On + (t & 1) * 16;

  for (int o0k = 0; o0k < On; o0k += 32) {
    V16 a0, a1, b0;
    a0.v = *(const uint4*)(aSrcH + o0k);
    a1.v = *(const uint4*)(aSrcL + o0k);
    b0.v = *(const uint4*)(bSrc + o0k);
    uint4 a0b = *(const uint4*)(aSrcH + o0k + 8);
    uint4 a1b = *(const uint4*)(aSrcL + o0k + 8);
    uint4 b0b = *(const uint4*)(bSrc + o0k + 8);
    __syncthreads();
    *(uint4*)&Ah[arow] = a0.v; *(uint4*)&Ah[arow + 8] = a0b;
    *(uint4*)&Al[arow] = a1.v; *(uint4*)&Al[arow + 8] = a1b;
    *(uint4*)&Bs[arow] = b0.v; *(uint4*)&Bs[arow + 8] = b0b;
    __syncthreads();

    v8s afh[4], afl[4], bf[4];
    const int lm = lane & 15, ko = (lane >> 4) * 8;
    #pragma unroll
    for (int i = 0; i < 4; ++i) {
      afh[i] = *(v8s*)&Ah[(wr * 64 + i * 16 + lm) * LDA + ko];
      afl[i] = *(v8s*)&Al[(wr * 64 + i * 16 + lm) * LDA + ko];
      bf[i]  = *(v8s*)&Bs[(wc * 64 + i * 16 + lm) * LDA + ko];
    }
    #pragma unroll
    for (int mi = 0; mi < 4; ++mi)
      #pragma unroll
      for (int nj = 0; nj < 4; ++nj) {
        acc[mi][nj] = __builtin_amdgcn_mfma_f32_16x16x32_bf16(afh[mi], bf[nj], acc[mi][nj], 0, 0, 0);
        acc[mi][nj] = __builtin_amdgcn_mfma_f32_16x16x32_bf16(afl[mi], bf[nj], acc[mi][nj], 0, 0, 0);
      }
  }

  const int lm = lane & 15;
  const int prow = wr * 64 + (lane >> 4) * 4;
  #pragma unroll
  for (int mi = 0; mi < 4; ++mi) {
    v4f m0 = vmax4(acc[mi][0], acc[mi][1]);
    v4f m1 = vmax4(acc[mi][2], acc[mi][3]);
    float v0[4], v1[4];
    #pragma unroll
    for (int r = 0; r < 4; ++r) {
      float a0 = m0[r], a1 = m1[r];
      #pragma unroll
      for (int msk = 1; msk < 16; msk <<= 1) {
        a0 = fmaxf(a0, __shfl_xor(a0, msk, 64));
        a1 = fmaxf(a1, __shfl_xor(a1, msk, 64));
      }
      v0[r] = a0; v1[r] = a1;
    }
    if (lm == 0) {
      #pragma unroll
      for (int r = 0; r < 4; ++r) {
        int p = prow + mi * 16 + r;
        float bias = b2s[p];
        size_t base = ((size_t)b * On + p0 + p) * Cn + c0 + wc * 2;
        feats[base]     = v0[r] + bias;
        feats[base + 1] = v1[r] + bias;
      }
    }
  }
}

extern "C" void kernel_launch(void* const* d_in, const int* in_sizes, int n_in,
                              void* d_out, int out_size, void* d_ws, size_t ws_size,
                              hipStream_t stream) {
  const float* x    = (const float*)d_in[0];
  const int*   sidx = (const int*)d_in[1];
  const float* W1   = (const float*)d_in[2];
  const float* b1   = (const float*)d_in[3];
  const float* W2   = (const float*)d_in[4];
  const float* b2   = (const float*)d_in[5];
  float* feats = (float*)d_out;                       // [B][OUT][C]
  float* out2  = (float*)d_out + FEATS_ELEMS;         // [B][S][C]

  char* ws = (char*)d_ws;
  float* d2   = (float*)(ws + D2_OFF);
  float* p2   = (float*)(ws + P2_OFF);
  int*   nbr  = (int*)  (ws + NBR_OFF);
  int*   cand = (int*)  (ws + CAND_OFF);
  int*   ccnt = (int*)  (ws + CNT_OFF);
  u16*   HT   = (u16*)  (ws + HT_OFF);
  u16*   xb   = (u16*)  (ws + XB_OFF);
  u16*   W1h  = (u16*)  (ws + W1H_OFF);
  u16*   W1l  = (u16*)  (ws + W1L_OFF);
  u16*   W2h  = (u16*)  (ws + W2H_OFF);
  u16*   W2l  = (u16*)  (ws + W2L_OFF);

  // KNN phase
  p2_kernel<<<dim3(Nn / 256), dim3(256), 0, stream>>>(x, p2);
  dist_kernel<<<dim3(Nn / 128, Sn / 128), dim3(256), 0, stream>>>(x, sidx, p2, d2);
  select_kernel<<<dim3(Sn), dim3(256), 0, stream>>>(d2, cand, ccnt);
  rerank_kernel<<<dim3(Sn), dim3(64), 0, stream>>>(x, sidx, cand, ccnt, nbr);
  // conversions (xb/HT overwrite the dead d2 region)
  cvt_x_kernel<<<dim3((Bn * Nn * Cn) / (256 * 8)), dim3(256), 0, stream>>>(x, xb);
  cvt_split_kernel<<<dim3((On * Sn) / (256 * 4)), dim3(256), 0, stream>>>(W1, W1h, W1l);
  cvt_split_kernel<<<dim3((On * On) / (256 * 4)), dim3(256), 0, stream>>>(W2, W2h, W2l);
  sample_kernel<<<dim3(SAMP_ELEMS / 256), dim3(256), 0, stream>>>(x, sidx, out2);
  // MFMA GEMMs
  gemm1_mfma<<<dim3(KCn / 128, On / 128, Bn), dim3(256), 0, stream>>>(xb, W1h, W1l, b1, nbr, HT);
  gemm2_mfma<<<dim3(Cn / 4, On / 128, Bn), dim3(256), 0, stream>>>(HT, W2h, W2l, b2, feats);
}